// Round 6
// baseline (1042.022 us; speedup 1.0000x reference)
//
#include <hip/hip_runtime.h>
#include <hip/hip_bf16.h>

typedef __hip_bfloat16 bf16;
typedef __attribute__((ext_vector_type(8))) short bf16x8;   // x32 MFMA A/B frag (4 VGPRs)
typedef __attribute__((ext_vector_type(4))) short bf16x4;   // x16 MFMA A/B frag (2 VGPRs)
typedef __attribute__((ext_vector_type(4))) float f32x4;    // MFMA C/D frag

// Problem constants (Attention_45681272160684)
#define BATCH 2
#define SEQ 2048
#define CDIM 2048
#define NH 16
#define NKV 4
#define HD 128

__device__ __forceinline__ float tof(float x)  { return x; }
__device__ __forceinline__ float tof(bf16 x)   { return __bfloat162float(x); }
__device__ __forceinline__ void  stf(float* p, float v) { *p = v; }
__device__ __forceinline__ void  stf(bf16* p,  float v) { *p = __float2bfloat16(v); }

__device__ __forceinline__ void gl_lds16(const bf16* g, bf16* l) {
    typedef const __attribute__((address_space(1))) unsigned int* gp_t;
    typedef __attribute__((address_space(3))) unsigned int* lp_t;
    __builtin_amdgcn_global_load_lds((gp_t)g, (lp_t)l, 16, 0, 0);
}

__device__ __forceinline__ f32x4 mfma16x16x16_bf16(bf16x4 a, bf16x4 b, f32x4 c) {
#if __has_builtin(__builtin_amdgcn_mfma_f32_16x16x16bf16_1k)
    return __builtin_amdgcn_mfma_f32_16x16x16bf16_1k(a, b, c, 0, 0, 0);
#else
    asm volatile("v_mfma_f32_16x16x16_bf16 %0, %1, %2, %0"
                 : "+v"(c) : "v"(a), "v"(b));
    return c;
#endif
}

__device__ __forceinline__ float fast_exp2(float x) {
#if __has_builtin(__builtin_amdgcn_exp2f)
    return __builtin_amdgcn_exp2f(x);
#else
    return exp2f(x);
#endif
}

// ---------------------------------------------------------------------------
// fp32 -> bf16 convert
// ---------------------------------------------------------------------------
__global__ __launch_bounds__(256) void f2b_kernel(const float* __restrict__ in,
                                                  bf16* __restrict__ out, int n4)
{
    int i = blockIdx.x * 256 + threadIdx.x;
    if (i >= n4) return;
    float4 v = *(const float4*)&in[(size_t)i * 4];
    bf16 o[4] = {__float2bfloat16(v.x), __float2bfloat16(v.y),
                 __float2bfloat16(v.z), __float2bfloat16(v.w)};
    *(ushort4*)&out[(size_t)i * 4] = *(ushort4*)o;
}

// ---------------------------------------------------------------------------
// Transposing convert: fp32 [R, Cn] -> bf16 [Cn, R]
// ---------------------------------------------------------------------------
__global__ __launch_bounds__(256) void transpose_f2b_kernel(
    const float* __restrict__ in, bf16* __restrict__ out, int R, int Cn)
{
    __shared__ float tile[64][65];
    const int r0 = blockIdx.y * 64, c0 = blockIdx.x * 64;
    for (int f = threadIdx.x; f < 4096; f += 256) {
        int r = f >> 6, c = f & 63;
        tile[r][c] = in[(size_t)(r0 + r) * Cn + c0 + c];
    }
    __syncthreads();
    for (int f = threadIdx.x; f < 4096; f += 256) {
        int r = f >> 6, c = f & 63;
        out[(size_t)(c0 + r) * R + r0 + c] = __float2bfloat16(tile[c][r]);
    }
}

// ---------------------------------------------------------------------------
// bf16 transpose per batch: Vr [B*SEQ, NKV*HD] -> Vt_g [(b*NKV+kvh)*HD + d][SEQ]
// ---------------------------------------------------------------------------
__global__ __launch_bounds__(256) void vtrans_kernel(
    const bf16* __restrict__ in, bf16* __restrict__ out)
{
    __shared__ bf16 tile[64][65];
    const int b = blockIdx.z;
    const int t0 = blockIdx.y * 64, c0 = blockIdx.x * 64;
    for (int f = threadIdx.x; f < 4096; f += 256) {
        int r = f >> 6, c = f & 63;
        tile[r][c] = in[(size_t)(b * SEQ + t0 + r) * (NKV * HD) + c0 + c];
    }
    __syncthreads();
    for (int f = threadIdx.x; f < 4096; f += 256) {
        int r = f >> 6, c = f & 63;
        out[(size_t)(b * NKV * HD + c0 + r) * SEQ + t0 + c] = tile[c][r];
    }
}

// ---------------------------------------------------------------------------
// MFMA GEMM: C[M,N] = A[M,K] @ Bt[N,K]^T (m97 structure) — unchanged, passing.
// ---------------------------------------------------------------------------
template <typename TC>
__global__ __launch_bounds__(256) void gemm_mfma_bt(
    const bf16* __restrict__ A, const bf16* __restrict__ Bt, TC* __restrict__ C,
    int M, int N, int K)
{
    __shared__ __align__(16) bf16 As[128 * 32];
    __shared__ __align__(16) bf16 Bs[128 * 32];

    const int tid = threadIdx.x;
    const int lane = tid & 63;
    const int wave = tid >> 6;
    const int m0 = blockIdx.y * 128;
    const int n0 = blockIdx.x * 128;
    const int wm = (wave >> 1) * 64;
    const int wn = (wave & 1) * 64;
    const int quad = lane >> 4;
    const int l16 = lane & 15;

    const int srow = tid >> 2;
    const int scol = (tid & 3) * 8;
    const bf16* Ag0 = A  + (size_t)(m0 + srow) * K + scol;
    const bf16* Ag1 = A  + (size_t)(m0 + srow + 64) * K + scol;
    const bf16* Bg0 = Bt + (size_t)(n0 + srow) * K + scol;
    const bf16* Bg1 = Bt + (size_t)(n0 + srow + 64) * K + scol;

    f32x4 acc[4][4];
#pragma unroll
    for (int mi = 0; mi < 4; ++mi)
#pragma unroll
        for (int ni = 0; ni < 4; ++ni)
            acc[mi][ni] = (f32x4){0.f, 0.f, 0.f, 0.f};

    for (int kt = 0; kt < K; kt += 32) {
        __syncthreads();
        gl_lds16(Ag0 + kt, &As[tid * 8]);
        gl_lds16(Ag1 + kt, &As[2048 + tid * 8]);
        gl_lds16(Bg0 + kt, &Bs[tid * 8]);
        gl_lds16(Bg1 + kt, &Bs[2048 + tid * 8]);
        __syncthreads();

        bf16x8 a[4], b[4];
#pragma unroll
        for (int mi = 0; mi < 4; ++mi)
            a[mi] = *(const bf16x8*)&As[(wm + mi * 16 + l16) * 32 + quad * 8];
#pragma unroll
        for (int ni = 0; ni < 4; ++ni)
            b[ni] = *(const bf16x8*)&Bs[(wn + ni * 16 + l16) * 32 + quad * 8];
#pragma unroll
        for (int mi = 0; mi < 4; ++mi)
#pragma unroll
            for (int ni = 0; ni < 4; ++ni)
                acc[mi][ni] = __builtin_amdgcn_mfma_f32_16x16x32_bf16(
                    a[mi], b[ni], acc[mi][ni], 0, 0, 0);
    }

#pragma unroll
    for (int mi = 0; mi < 4; ++mi)
#pragma unroll
        for (int ni = 0; ni < 4; ++ni) {
            int col = n0 + wn + ni * 16 + l16;
#pragma unroll
            for (int r = 0; r < 4; ++r) {
                int row = m0 + wm + mi * 16 + quad * 4 + r;
                stf(&C[(size_t)row * N + col], acc[mi][ni][r]);
            }
        }
}

// ---------------------------------------------------------------------------
// RoPE in place on [rows, ncols] bf16
// ---------------------------------------------------------------------------
__global__ __launch_bounds__(256) void rope_kernel(bf16* __restrict__ data,
                                                   int ncols, int total_pairs)
{
    int idx = blockIdx.x * 256 + threadIdx.x;
    if (idx >= total_pairs) return;
    int half = ncols >> 1;
    int row = idx / half;
    int p = idx - row * half;
    int head = p >> 6;
    int i = p & 63;
    int t = row & (SEQ - 1);
    float inv_ts = expf(-(float)i * 0.14391156831212787f);
    float angle = (float)t * inv_ts;
    float s, c;
    sincosf(angle, &s, &c);
    size_t base = (size_t)row * ncols + head * 128 + i;
    float x1 = __bfloat162float(data[base]);
    float x2 = __bfloat162float(data[base + 64]);
    data[base]      = __float2bfloat16(x1 * c - x2 * s);
    data[base + 64] = __float2bfloat16(x2 * c + x1 * s);
}

// ---------------------------------------------------------------------------
// Register-transpose MFMA flash attention: NO LDS, NO barriers, NO shuffles
// in the main loop. 4 waves/block, each wave owns 16 q-rows; key tiles of 64.
//   S^T = mfma_16x16x32(A=K, B=Q^T)  -> C-layout: row=key=quad*4+r, col=q=l16
//   (that register layout IS the x16 B-frag layout)
//   O^T += mfma_16x16x16(A=V^T-frag, B=P^T)  -> C-layout: row=d, col=q
// Softcap Pade + exp2 with log2(e) folded into the constants.
// ---------------------------------------------------------------------------
__global__ __launch_bounds__(256, 4) void attn_mfma3_kernel(
    const bf16* __restrict__ Q, const bf16* __restrict__ K,
    const bf16* __restrict__ Vt, bf16* __restrict__ Att)
{
    const int tid = threadIdx.x;
    const int lane = tid & 63;
    const int w = tid >> 6;
    const int quad = lane >> 4;
    const int l16 = lane & 15;
    const int bh = blockIdx.y;
    const int b = bh >> 4;
    const int hq = bh & 15;
    const int kvh = hq & 3;
    const int qt = (gridDim.x - 1) - blockIdx.x;   // heavy-first
    const int q0 = qt * 64 + w * 16;               // wave's 16 q-rows: q0 + l16

    // Q^T B-frags (x32): B[k=d=kk*32+quad*8+j][n=q=l16] — natural Qr rows
    const size_t qrow = (size_t)(b * SEQ + q0 + l16) * (NH * HD) + hq * HD;
    bf16x8 qf[4];
#pragma unroll
    for (int kk = 0; kk < 4; ++kk)
        qf[kk] = *(const bf16x8*)&Q[qrow + kk * 32 + quad * 8];

    const bf16* Kb = K  + (size_t)(b * SEQ) * (NKV * HD) + kvh * HD;  // row stride 512
    const bf16* Vb = Vt + (size_t)((b * NKV + kvh) * HD) * SEQ;       // row stride 2048

    f32x4 O[8];            // O^T tiles: row=d=dj*16+quad*4+r, col=q=l16
#pragma unroll
    for (int dj = 0; dj < 8; ++dj) O[dj] = (f32x4){0.f, 0.f, 0.f, 0.f};
    float lsum = 0.f;      // per-lane partial of sum_p for column q=l16

    const int ntiles = qt + 1;     // same for all 4 waves in the block
    for (int jt = 0; jt < ntiles; ++jt) {
        const int j0 = jt * 64;
        const bool diag = (jt == qt);

        // ---- S^T[64 key][16 q]: 4 m-tiles of 16 keys ----
        f32x4 sacc[4];
#pragma unroll
        for (int mt = 0; mt < 4; ++mt) {
            f32x4 s = (f32x4){0.f, 0.f, 0.f, 0.f};
            const bf16* krow = &Kb[(size_t)(j0 + mt * 16 + l16) * (NKV * HD)];
#pragma unroll
            for (int kk = 0; kk < 4; ++kk) {
                bf16x8 kf = *(const bf16x8*)&krow[kk * 32 + quad * 8];
                s = __builtin_amdgcn_mfma_f32_16x16x32_bf16(kf, qf[kk], s, 0, 0, 0);
            }
            sacc[mt] = s;
        }

        // ---- softcap (Pade, exp2-folded) + mask -> P^T frags in registers ----
        // p = exp2( u * fma(t2, 9.9627e-4, 8607.81) / fma(t2, 0.0703125, 67500) )
        //   == exp( 50*tanh(u/(sqrt(128)*50)) ), t2 = u^2
        bf16x4 pf[4];
#pragma unroll
        for (int mt = 0; mt < 4; ++mt) {
            bf16 pb[4];
#pragma unroll
            for (int r = 0; r < 4; ++r) {
                float u = sacc[mt][r];
                float t2 = u * u;
                float num = fmaf(t2, 9.96274e-4f, 8607.814f);
                float den = fmaf(t2, 0.0703125f, 67500.f);
                float s2 = u * num * __builtin_amdgcn_rcpf(den);
                float p = fast_exp2(s2);
                if (diag) {
                    int kl = mt * 16 + quad * 4 + r;   // key - j0
                    int ql = w * 16 + l16;             // q - qt*64
                    p = (kl <= ql) ? p : 0.f;
                }
                lsum += p;
                pb[r] = __float2bfloat16(p);
            }
            pf[mt] = *(bf16x4*)pb;
        }

        // ---- O^T += V^T @ P^T  (x16 MFMAs; V^T A-frags from global) ----
#pragma unroll
        for (int dj = 0; dj < 8; ++dj) {
            const bf16* vrow = &Vb[(size_t)(dj * 16 + l16) * SEQ + j0];
            f32x4 o = O[dj];
#pragma unroll
            for (int mt = 0; mt < 4; ++mt) {
                bf16x4 vf = *(const bf16x4*)&vrow[mt * 16 + quad * 4];
                o = mfma16x16x16_bf16(vf, pf[mt], o);
            }
            O[dj] = o;
        }
    }

    // ---- epilogue: total l per q (sum across quads), normalize, store ----
    lsum += __shfl_xor(lsum, 16);
    lsum += __shfl_xor(lsum, 32);
    float inv = 1.f / lsum;
    const size_t obase = (size_t)(b * SEQ + q0 + l16) * (NH * HD) + hq * HD;
#pragma unroll
    for (int dj = 0; dj < 8; ++dj) {
        bf16 ob[4];
#pragma unroll
        for (int r = 0; r < 4; ++r) ob[r] = __float2bfloat16(O[dj][r] * inv);
        *(ushort4*)&Att[obase + dj * 16 + quad * 4] = *(ushort4*)ob;
    }
}

// ---------------------------------------------------------------------------
extern "C" void kernel_launch(void* const* d_in, const int* in_sizes, int n_in,
                              void* d_out, int out_size, void* d_ws, size_t ws_size,
                              hipStream_t stream) {
    const float* x        = (const float*)d_in[0];
    // d_in[1] = mask: deterministic causal tril -> not read
    const float* q_kernel = (const float*)d_in[2];
    const float* k_kernel = (const float*)d_in[3];
    const float* v_kernel = (const float*)d_in[4];
    const float* o_kernel = (const float*)d_in[5];
    float* out = (float*)d_out;

    const int M = BATCH * SEQ;       // 4096
    char* ws = (char*)d_ws;
    bf16* xb   = (bf16*)ws;                              // 16 MB
    bf16* Att  = xb;                                     // alias: xb dead after V proj
    bf16* wqT  = (bf16*)(ws + 16777216);                 // 8 MB
    bf16* woT  = wqT;                                    // alias: wqT dead after Q proj
    bf16* wkT  = (bf16*)(ws + 25165824);                 // 2 MB
    bf16* wvT  = (bf16*)(ws + 27262976);                 // 2 MB
    bf16* Vt_g = wkT;                                    // alias: wk/wv dead after K/V proj
    bf16* Qr   = (bf16*)(ws + 29360128);                 // 16 MB
    bf16* Kr   = (bf16*)(ws + 46137344);                 // 4 MB
    bf16* Vr   = (bf16*)(ws + 50331648);                 // 4 MB

    f2b_kernel<<<(M * CDIM / 4 + 255) / 256, 256, 0, stream>>>(x, xb, M * CDIM / 4);
    transpose_f2b_kernel<<<dim3((NH * HD) / 64, CDIM / 64), 256, 0, stream>>>(
        q_kernel, wqT, CDIM, NH * HD);
    transpose_f2b_kernel<<<dim3((NKV * HD) / 64, CDIM / 64), 256, 0, stream>>>(
        k_kernel, wkT, CDIM, NKV * HD);
    transpose_f2b_kernel<<<dim3((NKV * HD) / 64, CDIM / 64), 256, 0, stream>>>(
        v_kernel, wvT, CDIM, NKV * HD);

    gemm_mfma_bt<bf16><<<dim3((NH * HD) / 128, M / 128), 256, 0, stream>>>(
        xb, wqT, Qr, M, NH * HD, CDIM);
    transpose_f2b_kernel<<<dim3(CDIM / 64, CDIM / 64), 256, 0, stream>>>(
        o_kernel, woT, CDIM, CDIM);
    gemm_mfma_bt<bf16><<<dim3((NKV * HD) / 128, M / 128), 256, 0, stream>>>(
        xb, wkT, Kr, M, NKV * HD, CDIM);
    gemm_mfma_bt<bf16><<<dim3((NKV * HD) / 128, M / 128), 256, 0, stream>>>(
        xb, wvT, Vr, M, NKV * HD, CDIM);

    {
        int pairs_q = M * (NH * HD / 2);
        rope_kernel<<<pairs_q / 256, 256, 0, stream>>>(Qr, NH * HD, pairs_q);
        int pairs_k = M * (NKV * HD / 2);
        rope_kernel<<<pairs_k / 256, 256, 0, stream>>>(Kr, NKV * HD, pairs_k);
    }

    // V transpose for attention A-operand (overwrites wkT/wvT - both dead)
    vtrans_kernel<<<dim3((NKV * HD) / 64, SEQ / 64, BATCH), 256, 0, stream>>>(Vr, Vt_g);

    // Register-transpose flash attention: 64 q/block, grid (T/64, B*NH)
    attn_mfma3_kernel<<<dim3(SEQ / 64, BATCH * NH), 256, 0, stream>>>(Qr, Kr, Vt_g, Att);

    gemm_mfma_bt<float><<<dim3(CDIM / 128, M / 128), 256, 0, stream>>>(
        Att, woT, out, M, CDIM, CDIM);
}

// Round 8
// 491.401 us; speedup vs baseline: 2.1205x; 2.1205x over previous
//
#include <hip/hip_runtime.h>
#include <hip/hip_bf16.h>

typedef __hip_bfloat16 bf16;
typedef __attribute__((ext_vector_type(8))) short bf16x8;   // x32 MFMA A/B frag (4 VGPRs)
typedef __attribute__((ext_vector_type(4))) short bf16x4;   // x16 MFMA A/B frag (2 VGPRs)
typedef __attribute__((ext_vector_type(4))) float f32x4;    // MFMA C/D frag

// Problem constants (Attention_45681272160684)
#define BATCH 2
#define SEQ 2048
#define CDIM 2048
#define NH 16
#define NKV 4
#define HD 128

__device__ __forceinline__ float tof(float x)  { return x; }
__device__ __forceinline__ float tof(bf16 x)   { return __bfloat162float(x); }
__device__ __forceinline__ void  stf(float* p, float v) { *p = v; }
__device__ __forceinline__ void  stf(bf16* p,  float v) { *p = __float2bfloat16(v); }

__device__ __forceinline__ void gl_lds16(const bf16* g, bf16* l) {
    typedef const __attribute__((address_space(1))) unsigned int* gp_t;
    typedef __attribute__((address_space(3))) unsigned int* lp_t;
    __builtin_amdgcn_global_load_lds((gp_t)g, (lp_t)l, 16, 0, 0);
}

__device__ __forceinline__ f32x4 mfma16x16x16_bf16(bf16x4 a, bf16x4 b, f32x4 c) {
#if __has_builtin(__builtin_amdgcn_mfma_f32_16x16x16bf16_1k)
    return __builtin_amdgcn_mfma_f32_16x16x16bf16_1k(a, b, c, 0, 0, 0);
#else
    asm volatile("v_mfma_f32_16x16x16_bf16 %0, %1, %2, %0"
                 : "+v"(c) : "v"(a), "v"(b));
    return c;
#endif
}

__device__ __forceinline__ float fast_exp2(float x) {
#if __has_builtin(__builtin_amdgcn_exp2f)
    return __builtin_amdgcn_exp2f(x);
#else
    return exp2f(x);
#endif
}

// ---------------------------------------------------------------------------
// fp32 -> bf16 convert
// ---------------------------------------------------------------------------
__global__ __launch_bounds__(256) void f2b_kernel(const float* __restrict__ in,
                                                  bf16* __restrict__ out, int n4)
{
    int i = blockIdx.x * 256 + threadIdx.x;
    if (i >= n4) return;
    float4 v = *(const float4*)&in[(size_t)i * 4];
    bf16 o[4] = {__float2bfloat16(v.x), __float2bfloat16(v.y),
                 __float2bfloat16(v.z), __float2bfloat16(v.w)};
    *(ushort4*)&out[(size_t)i * 4] = *(ushort4*)o;
}

// ---------------------------------------------------------------------------
// Transposing convert: fp32 [R, Cn] -> bf16 [Cn, R]
// ---------------------------------------------------------------------------
__global__ __launch_bounds__(256) void transpose_f2b_kernel(
    const float* __restrict__ in, bf16* __restrict__ out, int R, int Cn)
{
    __shared__ float tile[64][65];
    const int r0 = blockIdx.y * 64, c0 = blockIdx.x * 64;
    for (int f = threadIdx.x; f < 4096; f += 256) {
        int r = f >> 6, c = f & 63;
        tile[r][c] = in[(size_t)(r0 + r) * Cn + c0 + c];
    }
    __syncthreads();
    for (int f = threadIdx.x; f < 4096; f += 256) {
        int r = f >> 6, c = f & 63;
        out[(size_t)(c0 + r) * R + r0 + c] = __float2bfloat16(tile[c][r]);
    }
}

// ---------------------------------------------------------------------------
// bf16 transpose per batch: Vr [B*SEQ, NKV*HD] -> Vt_g [(b*NKV+kvh)*HD + d][SEQ]
// ---------------------------------------------------------------------------
__global__ __launch_bounds__(256) void vtrans_kernel(
    const bf16* __restrict__ in, bf16* __restrict__ out)
{
    __shared__ bf16 tile[64][65];
    const int b = blockIdx.z;
    const int t0 = blockIdx.y * 64, c0 = blockIdx.x * 64;
    for (int f = threadIdx.x; f < 4096; f += 256) {
        int r = f >> 6, c = f & 63;
        tile[r][c] = in[(size_t)(b * SEQ + t0 + r) * (NKV * HD) + c0 + c];
    }
    __syncthreads();
    for (int f = threadIdx.x; f < 4096; f += 256) {
        int r = f >> 6, c = f & 63;
        out[(size_t)(b * NKV * HD + c0 + r) * SEQ + t0 + c] = tile[c][r];
    }
}

// ---------------------------------------------------------------------------
// MFMA GEMM: C[M,N] = A[M,K] @ Bt[N,K]^T (m97 structure) — unchanged, passing.
// ---------------------------------------------------------------------------
template <typename TC>
__global__ __launch_bounds__(256) void gemm_mfma_bt(
    const bf16* __restrict__ A, const bf16* __restrict__ Bt, TC* __restrict__ C,
    int M, int N, int K)
{
    __shared__ __align__(16) bf16 As[128 * 32];
    __shared__ __align__(16) bf16 Bs[128 * 32];

    const int tid = threadIdx.x;
    const int lane = tid & 63;
    const int wave = tid >> 6;
    const int m0 = blockIdx.y * 128;
    const int n0 = blockIdx.x * 128;
    const int wm = (wave >> 1) * 64;
    const int wn = (wave & 1) * 64;
    const int quad = lane >> 4;
    const int l16 = lane & 15;

    const int srow = tid >> 2;
    const int scol = (tid & 3) * 8;
    const bf16* Ag0 = A  + (size_t)(m0 + srow) * K + scol;
    const bf16* Ag1 = A  + (size_t)(m0 + srow + 64) * K + scol;
    const bf16* Bg0 = Bt + (size_t)(n0 + srow) * K + scol;
    const bf16* Bg1 = Bt + (size_t)(n0 + srow + 64) * K + scol;

    f32x4 acc[4][4];
#pragma unroll
    for (int mi = 0; mi < 4; ++mi)
#pragma unroll
        for (int ni = 0; ni < 4; ++ni)
            acc[mi][ni] = (f32x4){0.f, 0.f, 0.f, 0.f};

    for (int kt = 0; kt < K; kt += 32) {
        __syncthreads();
        gl_lds16(Ag0 + kt, &As[tid * 8]);
        gl_lds16(Ag1 + kt, &As[2048 + tid * 8]);
        gl_lds16(Bg0 + kt, &Bs[tid * 8]);
        gl_lds16(Bg1 + kt, &Bs[2048 + tid * 8]);
        __syncthreads();

        bf16x8 a[4], b[4];
#pragma unroll
        for (int mi = 0; mi < 4; ++mi)
            a[mi] = *(const bf16x8*)&As[(wm + mi * 16 + l16) * 32 + quad * 8];
#pragma unroll
        for (int ni = 0; ni < 4; ++ni)
            b[ni] = *(const bf16x8*)&Bs[(wn + ni * 16 + l16) * 32 + quad * 8];
#pragma unroll
        for (int mi = 0; mi < 4; ++mi)
#pragma unroll
            for (int ni = 0; ni < 4; ++ni)
                acc[mi][ni] = __builtin_amdgcn_mfma_f32_16x16x32_bf16(
                    a[mi], b[ni], acc[mi][ni], 0, 0, 0);
    }

#pragma unroll
    for (int mi = 0; mi < 4; ++mi)
#pragma unroll
        for (int ni = 0; ni < 4; ++ni) {
            int col = n0 + wn + ni * 16 + l16;
#pragma unroll
            for (int r = 0; r < 4; ++r) {
                int row = m0 + wm + mi * 16 + quad * 4 + r;
                stf(&C[(size_t)row * N + col], acc[mi][ni][r]);
            }
        }
}

// ---------------------------------------------------------------------------
// RoPE in place on [rows, ncols] bf16
// ---------------------------------------------------------------------------
__global__ __launch_bounds__(256) void rope_kernel(bf16* __restrict__ data,
                                                   int ncols, int total_pairs)
{
    int idx = blockIdx.x * 256 + threadIdx.x;
    if (idx >= total_pairs) return;
    int half = ncols >> 1;
    int row = idx / half;
    int p = idx - row * half;
    int head = p >> 6;
    int i = p & 63;
    int t = row & (SEQ - 1);
    float inv_ts = expf(-(float)i * 0.14391156831212787f);
    float angle = (float)t * inv_ts;
    float s, c;
    sincosf(angle, &s, &c);
    size_t base = (size_t)row * ncols + head * 128 + i;
    float x1 = __bfloat162float(data[base]);
    float x2 = __bfloat162float(data[base + 64]);
    data[base]      = __float2bfloat16(x1 * c - x2 * s);
    data[base + 64] = __float2bfloat16(x2 * c + x1 * s);
}

// ---------------------------------------------------------------------------
// LDS-staged register-transpose MFMA flash attention.
// Block = 4 waves = (2 key-halves kw) x (2 q-halves qw); 64 q-rows/block,
// key tiles of 64. K + V^T staged via global_load_lds (coalesced, XOR-swizzled
// chunk placement to break stride-256B bank aliasing). S^T register trick:
//   S^T = x32 mfma(A=K, B=Q^T) -> C: row=key=quad*4+r, col=q=l16
//   P^T (= x16 B-frag layout) stays in registers; O^T += x16 mfma(V^T, P^T).
// No-max softmax (softcap |s|<=50) => key-split partials combine by plain sum.
// ---------------------------------------------------------------------------
__global__ __launch_bounds__(256, 3) void attn_mfma4_kernel(
    const bf16* __restrict__ Q, const bf16* __restrict__ K,
    const bf16* __restrict__ Vt, bf16* __restrict__ Att)
{
    __shared__ __align__(16) char smem[34816];       // Ks 16K | Vts 16K, reused as CB
    bf16* Ks  = (bf16*)smem;                         // [64 key][128 d] 16B-chunk-swizzled
    bf16* Vts = (bf16*)(smem + 16384);               // [128 d][64 key] 16B-chunk-swizzled
    float* CB = (float*)smem;                        // combine overlay (34816 B)
    __shared__ float lbuf[2][2][16];                 // [qw][g][l16] partial l from kw=0

    const int tid = threadIdx.x;
    const int lane = tid & 63;
    const int w = tid >> 6;
    const int kw = w >> 1;            // key half (0: keys 0-31, 1: 32-63 of tile)
    const int qw = w & 1;             // q half (32 q each)
    const int quad = lane >> 4;
    const int l16 = lane & 15;
    const int bh = blockIdx.y;
    const int b = bh >> 4;
    const int hq = bh & 15;
    const int kvh = hq & 3;
    const int qt = (gridDim.x - 1) - blockIdx.x;     // heavy-first
    const int q0 = qt * 64 + qw * 32;                // wave's q rows: q0 + g*16 + l16

    // Q^T B-frags (x32): two 16-q column groups
    bf16x8 qf[2][4];
#pragma unroll
    for (int g = 0; g < 2; ++g) {
        size_t qrow = (size_t)(b * SEQ + q0 + g * 16 + l16) * (NH * HD) + hq * HD;
#pragma unroll
        for (int kk = 0; kk < 4; ++kk)
            qf[g][kk] = *(const bf16x8*)&Q[qrow + kk * 32 + quad * 8];
    }

    const bf16* Kb = K  + (size_t)(b * SEQ) * (NKV * HD) + kvh * HD;  // row 512 elems
    const bf16* Vb = Vt + (size_t)((b * NKV + kvh) * HD) * SEQ;       // row 2048 elems

    f32x4 O[2][8];   // O^T partial (this wave's key half): row=d=dj*16+quad*4+r, col=q
#pragma unroll
    for (int g = 0; g < 2; ++g)
#pragma unroll
        for (int dj = 0; dj < 8; ++dj) O[g][dj] = (f32x4){0.f, 0.f, 0.f, 0.f};
    float lsum[2] = {0.f, 0.f};

    // staging index precompute (linear-in-tid LDS dest; XOR swizzle in source)
    const int srowK = tid >> 4;                 // key-within-16-group
    const int sgcK  = (tid & 15) ^ srowK;       // swizzled d-chunk
    const int srowV = tid >> 3;                 // d-within-32-group
    const int sgcV  = (tid & 7) ^ (srowV & 7);  // swizzled key-chunk

    const int ntiles = qt + 1;
    for (int jt = 0; jt < ntiles; ++jt) {
        const int j0 = jt * 64;
        __syncthreads();   // previous tile's readers done
#pragma unroll
        for (int c = 0; c < 4; ++c) {
            gl_lds16(Kb + (size_t)(j0 + c * 16 + srowK) * (NKV * HD) + sgcK * 8,
                     Ks + c * 2048 + tid * 8);
            gl_lds16(Vb + (size_t)(c * 32 + srowV) * SEQ + j0 + sgcV * 8,
                     Vts + c * 2048 + tid * 8);
        }
        __syncthreads();   // vmcnt drained, tiles visible

        // ---- S^T[32 key][32 q]: A=K frags (swizzle-read), B=Q^T regs ----
        f32x4 sacc[2][2];
#pragma unroll
        for (int mt = 0; mt < 2; ++mt) {
#pragma unroll
            for (int g = 0; g < 2; ++g) sacc[mt][g] = (f32x4){0.f, 0.f, 0.f, 0.f};
            const int krow = (kw * 32 + mt * 16 + l16) * 128;
#pragma unroll
            for (int kk = 0; kk < 4; ++kk) {
                bf16x8 kf = *(const bf16x8*)&Ks[krow + (((kk * 4 + quad) ^ l16) * 8)];
#pragma unroll
                for (int g = 0; g < 2; ++g)
                    sacc[mt][g] = __builtin_amdgcn_mfma_f32_16x16x32_bf16(
                        kf, qf[g][kk], sacc[mt][g], 0, 0, 0);
            }
        }

        // ---- softcap (Pade, exp2-folded) + mask -> P^T frags (registers) ----
        const bool diag = (jt == qt);
        bf16x4 pf[2][2];
#pragma unroll
        for (int mt = 0; mt < 2; ++mt)
#pragma unroll
            for (int g = 0; g < 2; ++g) {
                bf16 pb[4];
#pragma unroll
                for (int r = 0; r < 4; ++r) {
                    float u = sacc[mt][g][r];
                    float t2 = u * u;
                    float num = fmaf(t2, 9.96274e-4f, 8607.814f);
                    float den = fmaf(t2, 0.0703125f, 67500.f);
                    float s2 = u * num * __builtin_amdgcn_rcpf(den);
                    float p = fast_exp2(s2);     // exp(50*tanh(u/(sqrt(128)*50)))
                    if (diag) {
                        int kl = kw * 32 + mt * 16 + quad * 4 + r;
                        int ql = qw * 32 + g * 16 + l16;
                        p = (kl <= ql) ? p : 0.f;
                    }
                    lsum[g] += p;
                    pb[r] = __float2bfloat16(p);
                }
                pf[mt][g] = *(bf16x4*)pb;
            }

        // ---- O^T += V^T @ P^T (x16; V^T frags from swizzled LDS) ----
#pragma unroll
        for (int dj = 0; dj < 8; ++dj) {
            const int vrow = (dj * 16 + l16) * 64;
            const int dl7 = l16 & 7;
#pragma unroll
            for (int mt = 0; mt < 2; ++mt) {
                int c16 = kw * 4 + mt * 2 + (quad >> 1);
                bf16x4 vf = *(const bf16x4*)&Vts[vrow + ((c16 ^ dl7) << 3)
                                                 + (quad & 1) * 4];
#pragma unroll
                for (int g = 0; g < 2; ++g)
                    O[g][dj] = mfma16x16x16_bf16(vf, pf[mt][g], O[g][dj]);
            }
        }
    }

    // ---- combine key halves (no-max softmax: plain sums), normalize, store ----
    float lg[2];
#pragma unroll
    for (int g = 0; g < 2; ++g) {
        float v = lsum[g];
        v += __shfl_xor(v, 16);
        v += __shfl_xor(v, 32);
        lg[g] = v;                    // wave-total l for column (g, l16)
    }
    __syncthreads();                  // staging area free -> reuse as CB
    if (kw == 0) {
#pragma unroll
        for (int g = 0; g < 2; ++g) {
#pragma unroll
            for (int dj = 0; dj < 8; ++dj) {
                int basei = ((qw * 2 + g) * 8 + dj) * 272;
#pragma unroll
                for (int r = 0; r < 4; ++r)
                    CB[basei + (quad * 4 + r) * 17 + l16] = O[g][dj][r];
            }
            if (quad == 0) lbuf[qw][g][l16] = lg[g];
        }
    }
    __syncthreads();
    if (kw == 1) {
#pragma unroll
        for (int g = 0; g < 2; ++g) {
            float inv = 1.f / (lg[g] + lbuf[qw][g][l16]);
            size_t obase = (size_t)(b * SEQ + q0 + g * 16 + l16) * (NH * HD) + hq * HD;
#pragma unroll
            for (int dj = 0; dj < 8; ++dj) {
                int basei = ((qw * 2 + g) * 8 + dj) * 272;
                bf16 ob[4];
#pragma unroll
                for (int r = 0; r < 4; ++r) {
                    float v = O[g][dj][r] + CB[basei + (quad * 4 + r) * 17 + l16];
                    ob[r] = __float2bfloat16(v * inv);
                }
                *(ushort4*)&Att[obase + dj * 16 + quad * 4] = *(ushort4*)ob;
            }
        }
    }
}

// ---------------------------------------------------------------------------
extern "C" void kernel_launch(void* const* d_in, const int* in_sizes, int n_in,
                              void* d_out, int out_size, void* d_ws, size_t ws_size,
                              hipStream_t stream) {
    const float* x        = (const float*)d_in[0];
    // d_in[1] = mask: deterministic causal tril -> not read
    const float* q_kernel = (const float*)d_in[2];
    const float* k_kernel = (const float*)d_in[3];
    const float* v_kernel = (const float*)d_in[4];
    const float* o_kernel = (const float*)d_in[5];
    float* out = (float*)d_out;

    const int M = BATCH * SEQ;       // 4096
    char* ws = (char*)d_ws;
    bf16* xb   = (bf16*)ws;                              // 16 MB
    bf16* Att  = xb;                                     // alias: xb dead after V proj
    bf16* wqT  = (bf16*)(ws + 16777216);                 // 8 MB
    bf16* woT  = wqT;                                    // alias: wqT dead after Q proj
    bf16* wkT  = (bf16*)(ws + 25165824);                 // 2 MB
    bf16* wvT  = (bf16*)(ws + 27262976);                 // 2 MB
    bf16* Vt_g = wkT;                                    // alias: wk/wv dead after K/V proj
    bf16* Qr   = (bf16*)(ws + 29360128);                 // 16 MB
    bf16* Kr   = (bf16*)(ws + 46137344);                 // 4 MB
    bf16* Vr   = (bf16*)(ws + 50331648);                 // 4 MB

    f2b_kernel<<<(M * CDIM / 4 + 255) / 256, 256, 0, stream>>>(x, xb, M * CDIM / 4);
    transpose_f2b_kernel<<<dim3((NH * HD) / 64, CDIM / 64), 256, 0, stream>>>(
        q_kernel, wqT, CDIM, NH * HD);
    transpose_f2b_kernel<<<dim3((NKV * HD) / 64, CDIM / 64), 256, 0, stream>>>(
        k_kernel, wkT, CDIM, NKV * HD);
    transpose_f2b_kernel<<<dim3((NKV * HD) / 64, CDIM / 64), 256, 0, stream>>>(
        v_kernel, wvT, CDIM, NKV * HD);

    gemm_mfma_bt<bf16><<<dim3((NH * HD) / 128, M / 128), 256, 0, stream>>>(
        xb, wqT, Qr, M, NH * HD, CDIM);
    transpose_f2b_kernel<<<dim3(CDIM / 64, CDIM / 64), 256, 0, stream>>>(
        o_kernel, woT, CDIM, CDIM);
    gemm_mfma_bt<bf16><<<dim3((NKV * HD) / 128, M / 128), 256, 0, stream>>>(
        xb, wkT, Kr, M, NKV * HD, CDIM);
    gemm_mfma_bt<bf16><<<dim3((NKV * HD) / 128, M / 128), 256, 0, stream>>>(
        xb, wvT, Vr, M, NKV * HD, CDIM);

    {
        int pairs_q = M * (NH * HD / 2);
        rope_kernel<<<pairs_q / 256, 256, 0, stream>>>(Qr, NH * HD, pairs_q);
        int pairs_k = M * (NKV * HD / 2);
        rope_kernel<<<pairs_k / 256, 256, 0, stream>>>(Kr, NKV * HD, pairs_k);
    }

    // V transpose for attention (overwrites wkT/wvT - both dead)
    vtrans_kernel<<<dim3((NKV * HD) / 64, SEQ / 64, BATCH), 256, 0, stream>>>(Vr, Vt_g);

    // LDS-staged register-transpose flash attention: 64 q/block
    attn_mfma4_kernel<<<dim3(SEQ / 64, BATCH * NH), 256, 0, stream>>>(Qr, Kr, Vt_g, Att);

    gemm_mfma_bt<float><<<dim3(CDIM / 128, M / 128), 256, 0, stream>>>(
        Att, woT, out, M, CDIM, CDIM);
}